// Round 2
// baseline (5703.393 us; speedup 1.0000x reference)
//
#include <hip/hip_runtime.h>

#define B_  16
#define T_  12
#define N_  1024
#define K_  3
#define H_  64
#define DIN 65
#define KH  192   // K_*H_
#define OG  128   // 2*H_

// ---- workspace offsets (floats) ----
static const size_t OFF_H   = 0;                       // B*N*H   = 1048576
static const size_t OFF_Y   = 1048576;                 // B*N*KH  = 3145728
static const size_t OFF_Z   = 4194304;                 // B*N*KH
static const size_t OFF_ZB  = 7340032;                 // B*N*H
static const size_t OFF_RH  = 8388608;                 // B*N*H
static const size_t OFF_S1  = 9437184;                 // K*B*T*N = 589824
static const size_t OFF_S2  = 10027008;                // B*K*T*N = 589824
static const size_t OFF_WGH = 10616832;                // 192*128
static const size_t OFF_WUH = 10641408;                // 192*64
// total = 10653696 floats = 42.6 MB

// Repack W rows for the h-part: wgh[(k*64+c)*128+o] = Wg[(k*65+1+c)*128+o]
__global__ __launch_bounds__(256) void k_repack(const float* __restrict__ Wg,
                                                const float* __restrict__ Wu,
                                                float* __restrict__ wgh,
                                                float* __restrict__ wuh) {
    int idx = blockIdx.x * 256 + threadIdx.x;
    if (idx < KH * OG) {
        int d = idx / OG, o = idx % OG;
        int k = d / H_, c = d % H_;
        wgh[idx] = Wg[(size_t)(k * DIN + 1 + c) * OG + o];
    } else {
        int j = idx - KH * OG;
        if (j < KH * H_) {
            int d = j / H_, o = j % H_;
            int k = d / H_, c = d % H_;
            wuh[j] = Wu[(size_t)(k * DIN + 1 + c) * H_ + o];
        }
    }
}

// S1[(k*192+m)*1024 + j] = sum_j' G[k][j][j'] * x[m*1024 + j']   (m = b*12+t)
__global__ __launch_bounds__(256) void k_s1(const float* __restrict__ G,
                                            const float* __restrict__ x,
                                            float* __restrict__ S1) {
    int bx = blockIdx.x;               // 3*16*3 = 144
    int k = bx / 48; int rem = bx % 48; int rt = rem / 3; int ct = rem % 3;
    int j0 = rt * 64, m0 = ct * 64;
    __shared__ float a_s[32][68];
    __shared__ float b_s[32][68];
    int tid = threadIdx.x;
    int ty = tid / 16, tx = tid % 16;
    const float* Gk = G + (size_t)k * N_ * N_;
    float acc[4][4] = {};
    for (int k0 = 0; k0 < N_; k0 += 32) {
        int r = tid / 8, seg = tid % 8;
        #pragma unroll
        for (int rr = 0; rr < 2; ++rr) {
            float4 v = *(const float4*)&Gk[(size_t)(j0 + rr * 32 + r) * N_ + k0 + seg * 4];
            a_s[seg*4+0][rr*32+r] = v.x; a_s[seg*4+1][rr*32+r] = v.y;
            a_s[seg*4+2][rr*32+r] = v.z; a_s[seg*4+3][rr*32+r] = v.w;
        }
        #pragma unroll
        for (int rr = 0; rr < 2; ++rr) {
            int m = rr * 32 + r;
            float4 v = *(const float4*)&x[(size_t)(m0 + m) * N_ + k0 + seg * 4];
            b_s[seg*4+0][m] = v.x; b_s[seg*4+1][m] = v.y;
            b_s[seg*4+2][m] = v.z; b_s[seg*4+3][m] = v.w;
        }
        __syncthreads();
        #pragma unroll
        for (int kk = 0; kk < 32; ++kk) {
            float af[4], bf[4];
            *(float4*)&af[0] = *(const float4*)&a_s[kk][ty * 4];
            *(float4*)&bf[0] = *(const float4*)&b_s[kk][tx * 4];
            #pragma unroll
            for (int u = 0; u < 4; ++u)
                #pragma unroll
                for (int v = 0; v < 4; ++v) acc[u][v] += af[u] * bf[v];
        }
        __syncthreads();
    }
    #pragma unroll
    for (int v = 0; v < 4; ++v) {
        float4 w = make_float4(acc[0][v], acc[1][v], acc[2][v], acc[3][v]);
        *(float4*)&S1[(size_t)(k * 192 + m0 + tx * 4 + v) * N_ + j0 + ty * 4] = w;
    }
}

// S2[((b*3+k)*12+t)*1024 + i] = sum_j A[b][i][j] * S1[(k*192 + b*12 + t)*1024 + j]
__global__ __launch_bounds__(256) void k_s2(const float* __restrict__ A,
                                            const float* __restrict__ S1,
                                            float* __restrict__ S2) {
    int bx = blockIdx.x;               // 16*16 = 256
    int b = bx >> 4, rt = bx & 15; int i0 = rt * 64;
    __shared__ float a_s[32][68];
    __shared__ float b_s[32][40];
    int tid = threadIdx.x;
    int ty = tid & 63, tx = tid >> 6;  // wave = fixed tx -> b reads broadcast
    const float* Ab = A + (size_t)b * N_ * N_;
    float acc[9] = {};
    for (int k0 = 0; k0 < N_; k0 += 32) {
        int r = tid / 8, seg = tid % 8;
        #pragma unroll
        for (int rr = 0; rr < 2; ++rr) {
            float4 v = *(const float4*)&Ab[(size_t)(i0 + rr * 32 + r) * N_ + k0 + seg * 4];
            a_s[seg*4+0][rr*32+r] = v.x; a_s[seg*4+1][rr*32+r] = v.y;
            a_s[seg*4+2][rr*32+r] = v.z; a_s[seg*4+3][rr*32+r] = v.w;
        }
        for (int idx = tid; idx < 36 * 8; idx += 256) {
            int col = idx >> 3, seg2 = idx & 7;
            int kq = col / 12, tq = col % 12;
            float4 v = *(const float4*)&S1[(size_t)(kq * 192 + b * T_ + tq) * N_ + k0 + seg2 * 4];
            b_s[seg2*4+0][col] = v.x; b_s[seg2*4+1][col] = v.y;
            b_s[seg2*4+2][col] = v.z; b_s[seg2*4+3][col] = v.w;
        }
        __syncthreads();
        #pragma unroll
        for (int kk = 0; kk < 32; ++kk) {
            float a = a_s[kk][ty];
            #pragma unroll
            for (int q = 0; q < 9; ++q) acc[q] += a * b_s[kk][tx * 9 + q];
        }
        __syncthreads();
    }
    #pragma unroll
    for (int q = 0; q < 9; ++q) {
        int col = tx * 9 + q; int kq = col / 12, tq = col % 12;
        S2[(size_t)((b * 3 + kq) * T_ + tq) * N_ + i0 + ty] = acc[q];
    }
}

// Y[(b*1024+i)*192 + k*64 + c] = sum_j G[k][i][j] * Hin[(b*1024+j)*64 + c]
__global__ __launch_bounds__(256) void k_gh(const float* __restrict__ G,
                                            const float* __restrict__ Hin,
                                            float* __restrict__ Y) {
    int bx = blockIdx.x;               // 48*8 = 384
    int inst = bx >> 3, rt = bx & 7;
    int b = inst / 3, k = inst % 3;
    int i0 = rt * 128;
    __shared__ float a_s[32][132];
    __shared__ float b_s[32][64];
    int tid = threadIdx.x, ty = tid / 16, tx = tid % 16;
    const float* Gk = G + (size_t)k * N_ * N_;
    const float* Hb = Hin + (size_t)b * N_ * H_;
    float acc[8][4] = {};
    for (int k0 = 0; k0 < N_; k0 += 32) {
        int r = tid / 8, seg = tid % 8;
        #pragma unroll
        for (int rr = 0; rr < 4; ++rr) {
            float4 v = *(const float4*)&Gk[(size_t)(i0 + rr * 32 + r) * N_ + k0 + seg * 4];
            a_s[seg*4+0][rr*32+r] = v.x; a_s[seg*4+1][rr*32+r] = v.y;
            a_s[seg*4+2][rr*32+r] = v.z; a_s[seg*4+3][rr*32+r] = v.w;
        }
        #pragma unroll
        for (int rr = 0; rr < 2; ++rr) {
            int idx = rr * 256 + tid;  // 512 float4s
            int kr = idx / 16, cs = idx % 16;
            *(float4*)&b_s[kr][cs * 4] = *(const float4*)&Hb[(size_t)(k0 + kr) * H_ + cs * 4];
        }
        __syncthreads();
        #pragma unroll
        for (int kk = 0; kk < 32; ++kk) {
            float af[8], bf[4];
            *(float4*)&af[0] = *(const float4*)&a_s[kk][ty * 8];
            *(float4*)&af[4] = *(const float4*)&a_s[kk][ty * 8 + 4];
            *(float4*)&bf[0] = *(const float4*)&b_s[kk][tx * 4];
            #pragma unroll
            for (int u = 0; u < 8; ++u)
                #pragma unroll
                for (int v = 0; v < 4; ++v) acc[u][v] += af[u] * bf[v];
        }
        __syncthreads();
    }
    float* Yb = Y + (size_t)b * N_ * KH + k * 64;
    #pragma unroll
    for (int u = 0; u < 8; ++u)
        *(float4*)&Yb[(size_t)(i0 + ty * 8 + u) * KH + tx * 4] = *(float4*)&acc[u][0];
}

// Z[(b*1024+i)*192 + c] = sum_j A[b][i][j] * Y[(b*1024+j)*192 + c]
__global__ __launch_bounds__(256) void k_az(const float* __restrict__ A,
                                            const float* __restrict__ Yin,
                                            float* __restrict__ Z) {
    int bx = blockIdx.x;               // 16*16 = 256
    int b = bx >> 4, rt = bx & 15;
    int i0 = rt * 64;
    __shared__ float a_s[32][68];
    __shared__ float b_s[32][192];
    int tid = threadIdx.x, ty = tid / 16, tx = tid % 16;
    const float* Ab = A + (size_t)b * N_ * N_;
    const float* Yb = Yin + (size_t)b * N_ * KH;
    float acc[4][12] = {};
    for (int k0 = 0; k0 < N_; k0 += 32) {
        int r = tid / 8, seg = tid % 8;
        #pragma unroll
        for (int rr = 0; rr < 2; ++rr) {
            float4 v = *(const float4*)&Ab[(size_t)(i0 + rr * 32 + r) * N_ + k0 + seg * 4];
            a_s[seg*4+0][rr*32+r] = v.x; a_s[seg*4+1][rr*32+r] = v.y;
            a_s[seg*4+2][rr*32+r] = v.z; a_s[seg*4+3][rr*32+r] = v.w;
        }
        #pragma unroll
        for (int it = 0; it < 6; ++it) {
            int idx = it * 256 + tid;  // 32*48 = 1536 float4s
            int kr = idx / 48, cs = idx % 48;
            *(float4*)&b_s[kr][cs * 4] = *(const float4*)&Yb[(size_t)(k0 + kr) * KH + cs * 4];
        }
        __syncthreads();
        #pragma unroll
        for (int kk = 0; kk < 32; ++kk) {
            float af[4], bf[12];
            *(float4*)&af[0] = *(const float4*)&a_s[kk][ty * 4];
            *(float4*)&bf[0] = *(const float4*)&b_s[kk][tx * 12];
            *(float4*)&bf[4] = *(const float4*)&b_s[kk][tx * 12 + 4];
            *(float4*)&bf[8] = *(const float4*)&b_s[kk][tx * 12 + 8];
            #pragma unroll
            for (int u = 0; u < 4; ++u)
                #pragma unroll
                for (int v = 0; v < 12; ++v) acc[u][v] += af[u] * bf[v];
        }
        __syncthreads();
    }
    float* Zb = Z + (size_t)b * N_ * KH;
    #pragma unroll
    for (int u = 0; u < 4; ++u)
        #pragma unroll
        for (int q = 0; q < 3; ++q)
            *(float4*)&Zb[(size_t)(i0 + ty * 4 + u) * KH + tx * 12 + q * 4] = *(float4*)&acc[u][q * 4];
}

// gate epilogue: zr = sigmoid(Z@Wgh + xt-part + bias); z stored; rh = r*h
__global__ __launch_bounds__(128) void k_zr(const float* __restrict__ Z,
                                            const float* __restrict__ wgh,
                                            const float* __restrict__ Wg,
                                            const float* __restrict__ bg,
                                            const float* __restrict__ S2,
                                            const float* __restrict__ h,
                                            float* __restrict__ zb,
                                            float* __restrict__ rh, int t) {
    int bx = blockIdx.x;               // 16*64 = 1024
    int b = bx >> 6, ib = bx & 63;
    int i0 = ib * 16;
    int o = threadIdx.x;               // [0,128)
    __shared__ float Zs[16][192];
    __shared__ float S2s[3][16];
    for (int idx = o; idx < 16 * 192; idx += 128) {
        int ii = idx / 192, d = idx % 192;
        Zs[ii][d] = Z[(size_t)(b * N_ + i0 + ii) * KH + d];
    }
    if (o < 48) {
        int k = o / 16, ii = o % 16;
        S2s[k][ii] = S2[(size_t)((b * 3 + k) * T_ + t) * N_ + i0 + ii];
    }
    __syncthreads();
    float wx0 = Wg[(size_t)(0 * DIN) * OG + o];
    float wx1 = Wg[(size_t)(1 * DIN) * OG + o];
    float wx2 = Wg[(size_t)(2 * DIN) * OG + o];
    float bias = bg[o];
    float acc[16];
    #pragma unroll
    for (int ii = 0; ii < 16; ++ii)
        acc[ii] = bias + wx0 * S2s[0][ii] + wx1 * S2s[1][ii] + wx2 * S2s[2][ii];
    for (int d = 0; d < 192; ++d) {
        float w = wgh[(size_t)d * OG + o];
        #pragma unroll
        for (int ii = 0; ii < 16; ++ii) acc[ii] += Zs[ii][d] * w;
    }
    #pragma unroll
    for (int ii = 0; ii < 16; ++ii) {
        float v = 1.0f / (1.0f + expf(-acc[ii]));
        size_t base = (size_t)(b * N_ + i0 + ii) * H_;
        if (o < H_) zb[base + o] = v;
        else        rh[base + o - H_] = v * h[base + o - H_];
    }
}

// update epilogue: hc = tanh(Z@Wuh + xt-part + bias); h = z*hc + (1-z)*h
__global__ __launch_bounds__(64) void k_upd(const float* __restrict__ Z,
                                            const float* __restrict__ wuh,
                                            const float* __restrict__ Wu,
                                            const float* __restrict__ bu,
                                            const float* __restrict__ S2,
                                            const float* __restrict__ zb,
                                            float* __restrict__ h, int t) {
    int bx = blockIdx.x;               // 1024
    int b = bx >> 6, ib = bx & 63;
    int i0 = ib * 16;
    int o = threadIdx.x;               // [0,64)
    __shared__ float Zs[16][192];
    __shared__ float S2s[3][16];
    for (int idx = o; idx < 16 * 192; idx += 64) {
        int ii = idx / 192, d = idx % 192;
        Zs[ii][d] = Z[(size_t)(b * N_ + i0 + ii) * KH + d];
    }
    if (o < 48) {
        int k = o / 16, ii = o % 16;
        S2s[k][ii] = S2[(size_t)((b * 3 + k) * T_ + t) * N_ + i0 + ii];
    }
    __syncthreads();
    float wx0 = Wu[(size_t)(0 * DIN) * H_ + o];
    float wx1 = Wu[(size_t)(1 * DIN) * H_ + o];
    float wx2 = Wu[(size_t)(2 * DIN) * H_ + o];
    float bias = bu[o];
    float acc[16];
    #pragma unroll
    for (int ii = 0; ii < 16; ++ii)
        acc[ii] = bias + wx0 * S2s[0][ii] + wx1 * S2s[1][ii] + wx2 * S2s[2][ii];
    for (int d = 0; d < 192; ++d) {
        float w = wuh[(size_t)d * H_ + o];
        #pragma unroll
        for (int ii = 0; ii < 16; ++ii) acc[ii] += Zs[ii][d] * w;
    }
    #pragma unroll
    for (int ii = 0; ii < 16; ++ii) {
        float hc = tanhf(acc[ii]);
        size_t idx2 = (size_t)(b * N_ + i0 + ii) * H_ + o;
        float z = zb[idx2], hold = h[idx2];
        h[idx2] = z * hc + (1.0f - z) * hold;
    }
}

// out[(b*12+tt)*1024 + i] = h[b][i][:] @ W_dec[:,tt] + b_dec[tt]
__global__ __launch_bounds__(256) void k_dec(const float* __restrict__ h,
                                             const float* __restrict__ Wd,
                                             const float* __restrict__ bd,
                                             float* __restrict__ out) {
    int bx = blockIdx.x;               // 16*16 = 256
    int b = bx >> 4, it = bx & 15; int i0 = it * 64;
    __shared__ float hs[64][65];
    __shared__ float Wds[64][12];
    __shared__ float bds[12];
    int tid = threadIdx.x;
    for (int idx = tid; idx < 4096; idx += 256) {
        int r = idx >> 6, c = idx & 63;
        hs[r][c] = h[(size_t)(b * N_ + i0 + r) * H_ + c];
    }
    for (int idx = tid; idx < 768; idx += 256)   // FIX: was `if (tid < 768)` with 256 threads
        Wds[idx / 12][idx % 12] = Wd[idx];
    if (tid < 12) bds[tid] = bd[tid];
    __syncthreads();
    for (int oidx = tid; oidx < 768; oidx += 256) {
        int i = oidx & 63, tt = oidx >> 6;
        float acc = bds[tt];
        #pragma unroll
        for (int c = 0; c < 64; ++c) acc += hs[i][c] * Wds[c][tt];
        out[(size_t)(b * T_ + tt) * N_ + i0 + i] = acc;
    }
}

extern "C" void kernel_launch(void* const* d_in, const int* in_sizes, int n_in,
                              void* d_out, int out_size, void* d_ws, size_t ws_size,
                              hipStream_t stream) {
    const float* x  = (const float*)d_in[0];
    const float* G  = (const float*)d_in[1];
    const float* A  = (const float*)d_in[2];
    const float* Wg = (const float*)d_in[3];
    const float* bg = (const float*)d_in[4];
    const float* Wu = (const float*)d_in[5];
    const float* bu = (const float*)d_in[6];
    const float* Wd = (const float*)d_in[7];
    const float* bd = (const float*)d_in[8];
    float* out = (float*)d_out;
    float* ws  = (float*)d_ws;

    float* h    = ws + OFF_H;
    float* Y    = ws + OFF_Y;
    float* Z    = ws + OFF_Z;
    float* zb   = ws + OFF_ZB;
    float* rh   = ws + OFF_RH;
    float* S1   = ws + OFF_S1;
    float* S2   = ws + OFF_S2;
    float* wgh  = ws + OFF_WGH;
    float* wuh  = ws + OFF_WUH;

    hipMemsetAsync(h, 0, (size_t)B_ * N_ * H_ * sizeof(float), stream);
    k_repack<<<144, 256, 0, stream>>>(Wg, Wu, wgh, wuh);
    k_s1<<<144, 256, 0, stream>>>(G, x, S1);
    k_s2<<<256, 256, 0, stream>>>(A, S1, S2);

    for (int t = 0; t < T_; ++t) {
        k_gh<<<384, 256, 0, stream>>>(G, h, Y);
        k_az<<<256, 256, 0, stream>>>(A, Y, Z);
        k_zr<<<1024, 128, 0, stream>>>(Z, wgh, Wg, bg, S2, h, zb, rh, t);
        k_gh<<<384, 256, 0, stream>>>(G, rh, Y);
        k_az<<<256, 256, 0, stream>>>(A, Y, Z);
        k_upd<<<1024, 64, 0, stream>>>(Z, wuh, Wu, bu, S2, zb, h, t);
    }
    k_dec<<<256, 256, 0, stream>>>(h, Wd, bd, out);
}

// Round 4
// 3159.976 us; speedup vs baseline: 1.8049x; 1.8049x over previous
//
#include <hip/hip_runtime.h>

#define B_  16
#define T_  12
#define N_  1024
#define K_  3
#define H_  64
#define DIN 65
#define KH  192   // K_*H_
#define OG  128   // 2*H_

typedef _Float16 f16x4 __attribute__((ext_vector_type(4)));
typedef float    f32x4 __attribute__((ext_vector_type(4)));

// ---- workspace offsets (float units), total 10,653,696 f = 42.6 MB (proven size) ----
static const size_t OFF_H   = 0;          // f32 h            [16][1024][64]   1,048,576
static const size_t OFF_Z   = 1048576;    // f32 Z (x1024)    [16][1024][192]  3,145,728
static const size_t OFF_ZB  = 4194304;    // f32 z-gate       [16][1024][64]   1,048,576
static const size_t OFF_S2  = 5242880;    // f32 S2 (x1024)   [16][3][12][1024]  589,824
static const size_t OFF_WGH = 5832704;    // f32 wgh (/1024)  [192][128]          24,576
static const size_t OFF_WUH = 5857280;    // f32 wuh (/1024)  [192][64]           12,288
static const size_t OFF_HTH = 5869568;    // f16 Ht hi  [16][64][1024]  (524,288 f)
static const size_t OFF_HTL = 6393856;    // f16 Ht lo
static const size_t OFF_YTH = 6918144;    // f16 Yt hi  [16][192][1024] (1,572,864 f)
static const size_t OFF_YTL = 8491008;    // f16 Yt lo
static const size_t OFF_S1H = 10063872;   // f16 S1 hi  [3][192][1024]  (294,912 f)
static const size_t OFF_S1L = 10358784;   // f16 S1 lo

// Vector-element-safe hi/lo split (assignment, not reference binding).
#define CVT2(src, dsth, dstl) { float _v = (src); _Float16 _h = (_Float16)_v; \
                                dsth = _h; dstl = (_Float16)(_v - (float)_h); }

// Repack W rows for the h-part, pre-divided by 1024 (A is scaled x1024).
__global__ __launch_bounds__(256) void k_repack(const float* __restrict__ Wg,
                                                const float* __restrict__ Wu,
                                                float* __restrict__ wgh,
                                                float* __restrict__ wuh) {
    const float inv = 1.0f / 1024.0f;
    int idx = blockIdx.x * 256 + threadIdx.x;
    if (idx < KH * OG) {
        int d = idx / OG, o = idx % OG;
        int k = d / H_, c = d % H_;
        wgh[idx] = Wg[(size_t)(k * DIN + 1 + c) * OG + o] * inv;
    } else {
        int j = idx - KH * OG;
        if (j < KH * H_) {
            int d = j / H_, o = j % H_;
            int k = d / H_, c = d % H_;
            wuh[j] = Wu[(size_t)(k * DIN + 1 + c) * H_ + o] * inv;
        }
    }
}

// S1[k][m][i] = sum_j G[k][i][j] * x[m][j]  -> f16 hi/lo, m = b*12+t
// MFMA: A = G_k (M=i), B = x^T (N=m). grid 96: bx = kk*32 + it*2 + nh
__global__ __launch_bounds__(256) void k_s1b(const float* __restrict__ G,
                                             const float* __restrict__ x,
                                             _Float16* __restrict__ S1H,
                                             _Float16* __restrict__ S1L) {
    int bx = blockIdx.x;
    int nh = bx & 1, it = (bx >> 1) & 15, kk = bx >> 5;
    int i0 = it * 64, m0 = nh * 96;
    __shared__ _Float16 sAh[64][72], sAl[64][72], sBh[96][72], sBl[96][72];
    int tid = threadIdx.x, wid = tid >> 6, lane = tid & 63, ln = lane & 15, kl = lane >> 4;
    const float* Gk = G + (size_t)kk * N_ * N_;
    f32x4 acc[6];
    #pragma unroll
    for (int n = 0; n < 6; ++n) acc[n] = (f32x4){0.f, 0.f, 0.f, 0.f};
    for (int kc = 0; kc < N_; kc += 64) {
        #pragma unroll
        for (int it2 = 0; it2 < 4; ++it2) {           // G: 64x64 f32
            int idx = it2 * 256 + tid;
            int row = idx >> 4, c4 = (idx & 15) * 4;
            float4 g = *(const float4*)&Gk[(size_t)(i0 + row) * N_ + kc + c4];
            f16x4 hv, lv;
            CVT2(g.x, hv.x, lv.x); CVT2(g.y, hv.y, lv.y);
            CVT2(g.z, hv.z, lv.z); CVT2(g.w, hv.w, lv.w);
            *(f16x4*)&sAh[row][c4] = hv; *(f16x4*)&sAl[row][c4] = lv;
        }
        #pragma unroll
        for (int it2 = 0; it2 < 6; ++it2) {           // x: 96x64 f32
            int idx = it2 * 256 + tid;
            int row = idx >> 4, c4 = (idx & 15) * 4;
            float4 g = *(const float4*)&x[(size_t)(m0 + row) * N_ + kc + c4];
            f16x4 hv, lv;
            CVT2(g.x, hv.x, lv.x); CVT2(g.y, hv.y, lv.y);
            CVT2(g.z, hv.z, lv.z); CVT2(g.w, hv.w, lv.w);
            *(f16x4*)&sBh[row][c4] = hv; *(f16x4*)&sBl[row][c4] = lv;
        }
        __syncthreads();
        #pragma unroll
        for (int ks = 0; ks < 4; ++ks) {
            int ko = ks * 16 + kl * 4;
            f16x4 ah = *(const f16x4*)&sAh[wid * 16 + ln][ko];
            f16x4 al = *(const f16x4*)&sAl[wid * 16 + ln][ko];
            #pragma unroll
            for (int n = 0; n < 6; ++n) {
                f16x4 bh = *(const f16x4*)&sBh[n * 16 + ln][ko];
                f16x4 bl = *(const f16x4*)&sBl[n * 16 + ln][ko];
                acc[n] = __builtin_amdgcn_mfma_f32_16x16x16f16(ah, bh, acc[n], 0, 0, 0);
                acc[n] = __builtin_amdgcn_mfma_f32_16x16x16f16(ah, bl, acc[n], 0, 0, 0);
                acc[n] = __builtin_amdgcn_mfma_f32_16x16x16f16(al, bh, acc[n], 0, 0, 0);
            }
        }
        __syncthreads();
    }
    #pragma unroll
    for (int n = 0; n < 6; ++n) {
        int m = m0 + n * 16 + ln;
        #pragma unroll
        for (int r = 0; r < 4; ++r) {
            int i = i0 + wid * 16 + kl * 4 + r;
            size_t g = (((size_t)kk * 192 + m) << 10) + i;
            CVT2(acc[n][r], S1H[g], S1L[g]);
        }
    }
}

// S2[b][k][t][i] = sum_j (1024*A[b][i][j]) * S1[k][b*12+t][j]   (f32, x1024)
// grid 256: bx = b*16 + it
__global__ __launch_bounds__(256) void k_s2b(const float* __restrict__ A,
                                             const _Float16* __restrict__ S1H,
                                             const _Float16* __restrict__ S1L,
                                             float* __restrict__ S2) {
    int bx = blockIdx.x;
    int it = bx & 15, b = bx >> 4;
    int i0 = it * 64;
    __shared__ _Float16 sAh[64][72], sAl[64][72], sBh[48][72], sBl[48][72];
    int tid = threadIdx.x, wid = tid >> 6, lane = tid & 63, ln = lane & 15, kl = lane >> 4;
    const float* Ab = A + (size_t)b * N_ * N_;
    f32x4 acc[3];
    #pragma unroll
    for (int n = 0; n < 3; ++n) acc[n] = (f32x4){0.f, 0.f, 0.f, 0.f};
    for (int kc = 0; kc < N_; kc += 64) {
        #pragma unroll
        for (int it2 = 0; it2 < 4; ++it2) {           // A: 64x64 f32, scaled x1024
            int idx = it2 * 256 + tid;
            int row = idx >> 4, c4 = (idx & 15) * 4;
            float4 a4 = *(const float4*)&Ab[(size_t)(i0 + row) * N_ + kc + c4];
            f16x4 hv, lv;
            CVT2(a4.x * 1024.0f, hv.x, lv.x); CVT2(a4.y * 1024.0f, hv.y, lv.y);
            CVT2(a4.z * 1024.0f, hv.z, lv.z); CVT2(a4.w * 1024.0f, hv.w, lv.w);
            *(f16x4*)&sAh[row][c4] = hv; *(f16x4*)&sAl[row][c4] = lv;
        }
        for (int idx = tid; idx < 288; idx += 256) {  // S1: 36 rows x 64 halves
            int row = idx >> 3, c8 = (idx & 7) * 8;
            int kq = row / 12, tq = row - kq * 12;
            size_t g = (((size_t)kq * 192 + b * T_ + tq) << 10) + kc + c8;
            *(uint4*)&sBh[row][c8] = *(const uint4*)&S1H[g];
            *(uint4*)&sBl[row][c8] = *(const uint4*)&S1L[g];
        }
        __syncthreads();
        #pragma unroll
        for (int ks = 0; ks < 4; ++ks) {
            int ko = ks * 16 + kl * 4;
            f16x4 ah = *(const f16x4*)&sAh[wid * 16 + ln][ko];
            f16x4 al = *(const f16x4*)&sAl[wid * 16 + ln][ko];
            #pragma unroll
            for (int n = 0; n < 3; ++n) {
                f16x4 bh = *(const f16x4*)&sBh[n * 16 + ln][ko];
                f16x4 bl = *(const f16x4*)&sBl[n * 16 + ln][ko];
                acc[n] = __builtin_amdgcn_mfma_f32_16x16x16f16(ah, bh, acc[n], 0, 0, 0);
                acc[n] = __builtin_amdgcn_mfma_f32_16x16x16f16(ah, bl, acc[n], 0, 0, 0);
                acc[n] = __builtin_amdgcn_mfma_f32_16x16x16f16(al, bh, acc[n], 0, 0, 0);
            }
        }
        __syncthreads();
    }
    #pragma unroll
    for (int n = 0; n < 3; ++n) {
        int col = n * 16 + ln;
        if (col < 36) {
            int kq = col / 12, tq = col - kq * 12;
            #pragma unroll
            for (int r = 0; r < 4; ++r) {
                int i = i0 + wid * 16 + kl * 4 + r;
                S2[(((size_t)(b * 3 + kq) * T_ + tq) << 10) + i] = acc[n][r];
            }
        }
    }
}

// Stage 1: Yt[b][k*64+c][i] = sum_j Ht[b][c][j] * G[k][i][j]  (f16 hi/lo out)
// MFMA: A = Ht (M=c, 64), B = G^T (N=i). grid 384: bx = ((kk*8+it)*16 + b)
__global__ __launch_bounds__(256) void k_gh2(const float* __restrict__ G,
                                             const _Float16* __restrict__ HtH,
                                             const _Float16* __restrict__ HtL,
                                             _Float16* __restrict__ YtH,
                                             _Float16* __restrict__ YtL) {
    int bx = blockIdx.x;
    int b = bx & 15, rest = bx >> 4;
    int it = rest & 7, kk = rest >> 3;
    int i0 = it * 128;
    __shared__ _Float16 sAh[64][72], sAl[64][72], sBh[128][72], sBl[128][72];
    int tid = threadIdx.x, wid = tid >> 6, lane = tid & 63, ln = lane & 15, kl = lane >> 4;
    const float* Gk = G + (size_t)kk * N_ * N_;
    const _Float16* Hh = HtH + ((size_t)b << 16);
    const _Float16* Hl = HtL + ((size_t)b << 16);
    f32x4 acc[4][2];
    #pragma unroll
    for (int m = 0; m < 4; ++m)
        #pragma unroll
        for (int n = 0; n < 2; ++n) acc[m][n] = (f32x4){0.f, 0.f, 0.f, 0.f};
    for (int kc = 0; kc < N_; kc += 64) {
        #pragma unroll
        for (int it2 = 0; it2 < 2; ++it2) {           // Ht: 64x64 halves x2
            int idx = it2 * 256 + tid;
            int row = idx >> 3, c8 = (idx & 7) * 8;
            size_t g = ((size_t)row << 10) + kc + c8;
            *(uint4*)&sAh[row][c8] = *(const uint4*)&Hh[g];
            *(uint4*)&sAl[row][c8] = *(const uint4*)&Hl[g];
        }
        #pragma unroll
        for (int it2 = 0; it2 < 8; ++it2) {           // G: 128x64 f32 -> cvt
            int idx = it2 * 256 + tid;
            int row = idx >> 4, c4 = (idx & 15) * 4;
            float4 g = *(const float4*)&Gk[(size_t)(i0 + row) * N_ + kc + c4];
            f16x4 hv, lv;
            CVT2(g.x, hv.x, lv.x); CVT2(g.y, hv.y, lv.y);
            CVT2(g.z, hv.z, lv.z); CVT2(g.w, hv.w, lv.w);
            *(f16x4*)&sBh[row][c4] = hv; *(f16x4*)&sBl[row][c4] = lv;
        }
        __syncthreads();
        #pragma unroll
        for (int ks = 0; ks < 4; ++ks) {
            int ko = ks * 16 + kl * 4;
            f16x4 ah[4], al[4], bh[2], bl[2];
            #pragma unroll
            for (int m = 0; m < 4; ++m) {
                ah[m] = *(const f16x4*)&sAh[m * 16 + ln][ko];
                al[m] = *(const f16x4*)&sAl[m * 16 + ln][ko];
            }
            #pragma unroll
            for (int n = 0; n < 2; ++n) {
                int rr = wid * 32 + n * 16 + ln;
                bh[n] = *(const f16x4*)&sBh[rr][ko];
                bl[n] = *(const f16x4*)&sBl[rr][ko];
            }
            #pragma unroll
            for (int m = 0; m < 4; ++m)
                #pragma unroll
                for (int n = 0; n < 2; ++n) {
                    acc[m][n] = __builtin_amdgcn_mfma_f32_16x16x16f16(ah[m], bh[n], acc[m][n], 0, 0, 0);
                    acc[m][n] = __builtin_amdgcn_mfma_f32_16x16x16f16(ah[m], bl[n], acc[m][n], 0, 0, 0);
                    acc[m][n] = __builtin_amdgcn_mfma_f32_16x16x16f16(al[m], bh[n], acc[m][n], 0, 0, 0);
                }
        }
        __syncthreads();
    }
    #pragma unroll
    for (int m = 0; m < 4; ++m)
        #pragma unroll
        for (int n = 0; n < 2; ++n) {
            int i = i0 + wid * 32 + n * 16 + ln;
            #pragma unroll
            for (int r = 0; r < 4; ++r) {
                int c = m * 16 + kl * 4 + r;
                size_t g = (((size_t)b * 192 + kk * 64 + c) << 10) + i;
                CVT2(acc[m][n][r], YtH[g], YtL[g]);
            }
        }
}

// Stage 2: Z[b][i][c] = sum_j (1024*A[b][i][j]) * Y[b][j][c]   (f32, x1024)
// MFMA: A = Adj (M=i), B = Yt (N=c). grid 512: bx = b*32 + it*2 + nh
__global__ __launch_bounds__(256) void k_az2(const float* __restrict__ A,
                                             const _Float16* __restrict__ YtH,
                                             const _Float16* __restrict__ YtL,
                                             float* __restrict__ Z) {
    int bx = blockIdx.x;
    int nh = bx & 1, it = (bx >> 1) & 15, b = bx >> 5;
    int i0 = it * 64, c0 = nh * 96;
    __shared__ _Float16 sAh[64][72], sAl[64][72], sBh[96][72], sBl[96][72];
    int tid = threadIdx.x, wid = tid >> 6, lane = tid & 63, ln = lane & 15, kl = lane >> 4;
    const float* Ab = A + (size_t)b * N_ * N_;
    const _Float16* Yh = YtH + (((size_t)b * 192 + c0) << 10);
    const _Float16* Yl = YtL + (((size_t)b * 192 + c0) << 10);
    f32x4 acc[6];
    #pragma unroll
    for (int n = 0; n < 6; ++n) acc[n] = (f32x4){0.f, 0.f, 0.f, 0.f};
    for (int kc = 0; kc < N_; kc += 64) {
        #pragma unroll
        for (int it2 = 0; it2 < 4; ++it2) {           // A: 64x64 f32, x1024
            int idx = it2 * 256 + tid;
            int row = idx >> 4, c4 = (idx & 15) * 4;
            float4 a4 = *(const float4*)&Ab[(size_t)(i0 + row) * N_ + kc + c4];
            f16x4 hv, lv;
            CVT2(a4.x * 1024.0f, hv.x, lv.x); CVT2(a4.y * 1024.0f, hv.y, lv.y);
            CVT2(a4.z * 1024.0f, hv.z, lv.z); CVT2(a4.w * 1024.0f, hv.w, lv.w);
            *(f16x4*)&sAh[row][c4] = hv; *(f16x4*)&sAl[row][c4] = lv;
        }
        #pragma unroll
        for (int it2 = 0; it2 < 3; ++it2) {           // Yt: 96x64 halves x2
            int idx = it2 * 256 + tid;
            int row = idx >> 3, c8 = (idx & 7) * 8;
            size_t g = ((size_t)row << 10) + kc + c8;
            *(uint4*)&sBh[row][c8] = *(const uint4*)&Yh[g];
            *(uint4*)&sBl[row][c8] = *(const uint4*)&Yl[g];
        }
        __syncthreads();
        #pragma unroll
        for (int ks = 0; ks < 4; ++ks) {
            int ko = ks * 16 + kl * 4;
            f16x4 ah = *(const f16x4*)&sAh[wid * 16 + ln][ko];
            f16x4 al = *(const f16x4*)&sAl[wid * 16 + ln][ko];
            #pragma unroll
            for (int n = 0; n < 6; ++n) {
                f16x4 bh = *(const f16x4*)&sBh[n * 16 + ln][ko];
                f16x4 bl = *(const f16x4*)&sBl[n * 16 + ln][ko];
                acc[n] = __builtin_amdgcn_mfma_f32_16x16x16f16(ah, bh, acc[n], 0, 0, 0);
                acc[n] = __builtin_amdgcn_mfma_f32_16x16x16f16(ah, bl, acc[n], 0, 0, 0);
                acc[n] = __builtin_amdgcn_mfma_f32_16x16x16f16(al, bh, acc[n], 0, 0, 0);
            }
        }
        __syncthreads();
    }
    #pragma unroll
    for (int n = 0; n < 6; ++n) {
        int c = c0 + n * 16 + ln;
        #pragma unroll
        for (int r = 0; r < 4; ++r) {
            int i = i0 + wid * 16 + kl * 4 + r;
            Z[((size_t)(b << 10) + i) * 192 + c] = acc[n][r];
        }
    }
}

// gate epilogue: zr = sigmoid(Z*wgh + S2*wx/1024 + bias); z->zb f32; r*h -> Ht f16 pair
__global__ __launch_bounds__(128) void k_zr(const float* __restrict__ Z,
                                            const float* __restrict__ wgh,
                                            const float* __restrict__ Wg,
                                            const float* __restrict__ bg,
                                            const float* __restrict__ S2,
                                            const float* __restrict__ h,
                                            float* __restrict__ zb,
                                            _Float16* __restrict__ HtH,
                                            _Float16* __restrict__ HtL, int t) {
    const float inv = 1.0f / 1024.0f;
    int bx = blockIdx.x;
    int b = bx >> 6, ib = bx & 63;
    int i0 = ib * 16;
    int o = threadIdx.x;
    __shared__ float Zs[16][192];
    __shared__ float S2s[3][16];
    for (int idx = o; idx < 16 * 192; idx += 128) {
        int ii = idx / 192, d = idx % 192;
        Zs[ii][d] = Z[(size_t)(b * N_ + i0 + ii) * KH + d];
    }
    if (o < 48) {
        int k = o / 16, ii = o % 16;
        S2s[k][ii] = S2[(size_t)((b * 3 + k) * T_ + t) * N_ + i0 + ii];
    }
    __syncthreads();
    float wx0 = Wg[(size_t)(0 * DIN) * OG + o] * inv;
    float wx1 = Wg[(size_t)(1 * DIN) * OG + o] * inv;
    float wx2 = Wg[(size_t)(2 * DIN) * OG + o] * inv;
    float bias = bg[o];
    float acc[16];
    #pragma unroll
    for (int ii = 0; ii < 16; ++ii)
        acc[ii] = bias + wx0 * S2s[0][ii] + wx1 * S2s[1][ii] + wx2 * S2s[2][ii];
    for (int d = 0; d < 192; ++d) {
        float w = wgh[(size_t)d * OG + o];
        #pragma unroll
        for (int ii = 0; ii < 16; ++ii) acc[ii] += Zs[ii][d] * w;
    }
    if (o < H_) {
        #pragma unroll
        for (int ii = 0; ii < 16; ++ii) {
            float v = 1.0f / (1.0f + expf(-acc[ii]));
            zb[(size_t)(b * N_ + i0 + ii) * H_ + o] = v;
        }
    } else {
        int c = o - H_;
        alignas(16) _Float16 hb[16], lb[16];
        #pragma unroll
        for (int ii = 0; ii < 16; ++ii) {
            float v = 1.0f / (1.0f + expf(-acc[ii]));
            float rv = v * h[(size_t)(b * N_ + i0 + ii) * H_ + c];
            CVT2(rv, hb[ii], lb[ii]);
        }
        size_t gt = ((size_t)(b * 64 + c) << 10) + i0;
        *(uint4*)&HtH[gt] = *(uint4*)&hb[0];
        *(uint4*)&HtH[gt + 8] = *(uint4*)&hb[8];
        *(uint4*)&HtL[gt] = *(uint4*)&lb[0];
        *(uint4*)&HtL[gt + 8] = *(uint4*)&lb[8];
    }
}

// update epilogue: hc = tanh(...); h = z*hc + (1-z)*h  (f32 + Ht f16 pair)
__global__ __launch_bounds__(64) void k_upd(const float* __restrict__ Z,
                                            const float* __restrict__ wuh,
                                            const float* __restrict__ Wu,
                                            const float* __restrict__ bu,
                                            const float* __restrict__ S2,
                                            const float* __restrict__ zb,
                                            float* __restrict__ h,
                                            _Float16* __restrict__ HtH,
                                            _Float16* __restrict__ HtL, int t) {
    const float inv = 1.0f / 1024.0f;
    int bx = blockIdx.x;
    int b = bx >> 6, ib = bx & 63;
    int i0 = ib * 16;
    int o = threadIdx.x;
    __shared__ float Zs[16][192];
    __shared__ float S2s[3][16];
    for (int idx = o; idx < 16 * 192; idx += 64) {
        int ii = idx / 192, d = idx % 192;
        Zs[ii][d] = Z[(size_t)(b * N_ + i0 + ii) * KH + d];
    }
    if (o < 48) {
        int k = o / 16, ii = o % 16;
        S2s[k][ii] = S2[(size_t)((b * 3 + k) * T_ + t) * N_ + i0 + ii];
    }
    __syncthreads();
    float wx0 = Wu[(size_t)(0 * DIN) * H_ + o] * inv;
    float wx1 = Wu[(size_t)(1 * DIN) * H_ + o] * inv;
    float wx2 = Wu[(size_t)(2 * DIN) * H_ + o] * inv;
    float bias = bu[o];
    float acc[16];
    #pragma unroll
    for (int ii = 0; ii < 16; ++ii)
        acc[ii] = bias + wx0 * S2s[0][ii] + wx1 * S2s[1][ii] + wx2 * S2s[2][ii];
    for (int d = 0; d < 192; ++d) {
        float w = wuh[(size_t)d * H_ + o];
        #pragma unroll
        for (int ii = 0; ii < 16; ++ii) acc[ii] += Zs[ii][d] * w;
    }
    alignas(16) _Float16 hb[16], lb[16];
    #pragma unroll
    for (int ii = 0; ii < 16; ++ii) {
        float hc = tanhf(acc[ii]);
        size_t idx2 = (size_t)(b * N_ + i0 + ii) * H_ + o;
        float z = zb[idx2], hold = h[idx2];
        float hn = z * hc + (1.0f - z) * hold;
        h[idx2] = hn;
        CVT2(hn, hb[ii], lb[ii]);
    }
    size_t gt = ((size_t)(b * 64 + o) << 10) + i0;
    *(uint4*)&HtH[gt] = *(uint4*)&hb[0];
    *(uint4*)&HtH[gt + 8] = *(uint4*)&hb[8];
    *(uint4*)&HtL[gt] = *(uint4*)&lb[0];
    *(uint4*)&HtL[gt + 8] = *(uint4*)&lb[8];
}

// out[(b*12+tt)*1024 + i] = h[b][i][:] @ W_dec[:,tt] + b_dec[tt]
__global__ __launch_bounds__(256) void k_dec(const float* __restrict__ h,
                                             const float* __restrict__ Wd,
                                             const float* __restrict__ bd,
                                             float* __restrict__ out) {
    int bx = blockIdx.x;
    int b = bx >> 4, it = bx & 15; int i0 = it * 64;
    __shared__ float hs[64][65];
    __shared__ float Wds[64][12];
    __shared__ float bds[12];
    int tid = threadIdx.x;
    for (int idx = tid; idx < 4096; idx += 256) {
        int r = idx >> 6, c = idx & 63;
        hs[r][c] = h[(size_t)(b * N_ + i0 + r) * H_ + c];
    }
    for (int idx = tid; idx < 768; idx += 256)
        Wds[idx / 12][idx % 12] = Wd[idx];
    if (tid < 12) bds[tid] = bd[tid];
    __syncthreads();
    for (int oidx = tid; oidx < 768; oidx += 256) {
        int i = oidx & 63, tt = oidx >> 6;
        float acc = bds[tt];
        #pragma unroll
        for (int c = 0; c < 64; ++c) acc += hs[i][c] * Wds[c][tt];
        out[(size_t)(b * T_ + tt) * N_ + i0 + i] = acc;
    }
}

extern "C" void kernel_launch(void* const* d_in, const int* in_sizes, int n_in,
                              void* d_out, int out_size, void* d_ws, size_t ws_size,
                              hipStream_t stream) {
    const float* x  = (const float*)d_in[0];
    const float* G  = (const float*)d_in[1];
    const float* A  = (const float*)d_in[2];
    const float* Wg = (const float*)d_in[3];
    const float* bg = (const float*)d_in[4];
    const float* Wu = (const float*)d_in[5];
    const float* bu = (const float*)d_in[6];
    const float* Wd = (const float*)d_in[7];
    const float* bd = (const float*)d_in[8];
    float* out = (float*)d_out;
    float* ws  = (float*)d_ws;

    float* h   = ws + OFF_H;
    float* Z   = ws + OFF_Z;
    float* zb  = ws + OFF_ZB;
    float* S2  = ws + OFF_S2;
    float* wgh = ws + OFF_WGH;
    float* wuh = ws + OFF_WUH;
    _Float16* HtH = (_Float16*)(ws + OFF_HTH);
    _Float16* HtL = (_Float16*)(ws + OFF_HTL);
    _Float16* YtH = (_Float16*)(ws + OFF_YTH);
    _Float16* YtL = (_Float16*)(ws + OFF_YTL);
    _Float16* S1H = (_Float16*)(ws + OFF_S1H);
    _Float16* S1L = (_Float16*)(ws + OFF_S1L);

    hipMemsetAsync(h, 0, (size_t)B_ * N_ * H_ * sizeof(float), stream);
    hipMemsetAsync((void*)HtH, 0, (size_t)2 * B_ * N_ * H_ * sizeof(_Float16), stream); // HtH+HtL adjacent
    k_repack<<<144, 256, 0, stream>>>(Wg, Wu, wgh, wuh);
    k_s1b<<<96, 256, 0, stream>>>(G, x, S1H, S1L);
    k_s2b<<<256, 256, 0, stream>>>(A, S1H, S1L, S2);

    for (int t = 0; t < T_; ++t) {
        k_gh2<<<384, 256, 0, stream>>>(G, HtH, HtL, YtH, YtL);
        k_az2<<<512, 256, 0, stream>>>(A, YtH, YtL, Z);
        k_zr<<<1024, 128, 0, stream>>>(Z, wgh, Wg, bg, S2, h, zb, HtH, HtL, t);
        k_gh2<<<384, 256, 0, stream>>>(G, HtH, HtL, YtH, YtL);
        k_az2<<<512, 256, 0, stream>>>(A, YtH, YtL, Z);
        k_upd<<<1024, 64, 0, stream>>>(Z, wuh, Wu, bu, S2, zb, h, HtH, HtL, t);
    }
    k_dec<<<256, 256, 0, stream>>>(h, Wd, bd, out);
}

// Round 5
// 1956.844 us; speedup vs baseline: 2.9146x; 1.6148x over previous
//
#include <hip/hip_runtime.h>

#define B_  16
#define T_  12
#define N_  1024
#define K_  3
#define H_  64
#define DIN 65
#define KH  192   // K_*H_
#define OG  128   // 2*H_

typedef _Float16 f16x4 __attribute__((ext_vector_type(4)));
typedef float    f32x4 __attribute__((ext_vector_type(4)));

// ---- workspace offsets (float units), total 6,670,912 f = 26.7 MB ----
static const size_t OFF_H   = 0;          // f32 h   [16][1024][64]
static const size_t OFF_ZB  = 1048576;    // f32 z   [16][1024][64]
static const size_t OFF_S2  = 2097152;    // f32 S2  [16][3][12][1024] (x1024)
static const size_t OFF_ZF  = 2686976;    // f16 Z   [16][1024][192]   (x1024)
static const size_t OFF_HT  = 4259840;    // f16 Ht  [16][64][1024]
static const size_t OFF_YT  = 4784128;    // f16 Yt  [16][192][1024]
static const size_t OFF_S1  = 6356992;    // f16 S1  [3][192][1024]
static const size_t OFF_WGT = 6651904;    // f16 wghT [128][192] (/1024)
static const size_t OFF_WUT = 6664192;    // f16 wuhT [64][192]  (/1024)
static const size_t OFF_WX  = 6670336;    // f32 wx: [0..383]=gate [3][128], [384..575]=upd [3][64] (/1024)

// Repack weights: transposed f16 h-part + f32 x-part rows, all pre-divided by 1024.
__global__ __launch_bounds__(256) void k_repack(const float* __restrict__ Wg,
                                                const float* __restrict__ Wu,
                                                _Float16* __restrict__ wghT,
                                                _Float16* __restrict__ wuhT,
                                                float* __restrict__ wx) {
    const float inv = 1.0f / 1024.0f;
    int idx = blockIdx.x * 256 + threadIdx.x;
    if (idx < 128 * 192) {                       // wghT[o][d], d = k*64+c
        int o = idx / 192, d = idx % 192;
        int k = d / 64, c = d % 64;
        wghT[idx] = (_Float16)(Wg[(size_t)(k * DIN + 1 + c) * OG + o] * inv);
    } else if (idx < 128 * 192 + 64 * 192) {     // wuhT[o][d]
        int j = idx - 128 * 192;
        int o = j / 192, d = j % 192;
        int k = d / 64, c = d % 64;
        wuhT[j] = (_Float16)(Wu[(size_t)(k * DIN + 1 + c) * H_ + o] * inv);
    } else if (idx < 128 * 192 + 64 * 192 + 576) {
        int j = idx - 128 * 192 - 64 * 192;
        if (j < 384) { int k = j >> 7, o = j & 127; wx[j] = Wg[(size_t)(k * DIN) * OG + o] * inv; }
        else { int j2 = j - 384; int k = j2 >> 6, o = j2 & 63; wx[j] = Wu[(size_t)(k * DIN) * H_ + o] * inv; }
    }
}

// S1[k][m][i] = sum_j G[k][i][j] x[m][j]  (f16 out). grid 96: kk*32 + it*2 + nh
__global__ __launch_bounds__(256) void k_s1b(const float* __restrict__ G,
                                             const float* __restrict__ x,
                                             _Float16* __restrict__ S1) {
    int bx = blockIdx.x;
    int nh = bx & 1, it = (bx >> 1) & 15, kk = bx >> 5;
    int i0 = it * 64, m0 = nh * 96;
    __shared__ _Float16 sA[64][72], sB[96][72];
    int tid = threadIdx.x, wid = tid >> 6, ln = tid & 15, kl = (tid & 63) >> 4;
    const float* Gk = G + (size_t)kk * N_ * N_;
    f32x4 acc[6];
    #pragma unroll
    for (int n = 0; n < 6; ++n) acc[n] = (f32x4){0.f, 0.f, 0.f, 0.f};
    for (int kc = 0; kc < N_; kc += 64) {
        #pragma unroll
        for (int it2 = 0; it2 < 4; ++it2) {
            int idx = it2 * 256 + tid; int row = idx >> 4, c4 = (idx & 15) * 4;
            float4 g = *(const float4*)&Gk[(size_t)(i0 + row) * N_ + kc + c4];
            f16x4 hv = {(_Float16)g.x, (_Float16)g.y, (_Float16)g.z, (_Float16)g.w};
            *(f16x4*)&sA[row][c4] = hv;
        }
        #pragma unroll
        for (int it2 = 0; it2 < 6; ++it2) {
            int idx = it2 * 256 + tid; int row = idx >> 4, c4 = (idx & 15) * 4;
            float4 g = *(const float4*)&x[(size_t)(m0 + row) * N_ + kc + c4];
            f16x4 hv = {(_Float16)g.x, (_Float16)g.y, (_Float16)g.z, (_Float16)g.w};
            *(f16x4*)&sB[row][c4] = hv;
        }
        __syncthreads();
        #pragma unroll
        for (int ks = 0; ks < 4; ++ks) {
            int ko = ks * 16 + kl * 4;
            f16x4 a = *(const f16x4*)&sA[wid * 16 + ln][ko];
            #pragma unroll
            for (int n = 0; n < 6; ++n) {
                f16x4 b = *(const f16x4*)&sB[n * 16 + ln][ko];
                acc[n] = __builtin_amdgcn_mfma_f32_16x16x16f16(a, b, acc[n], 0, 0, 0);
            }
        }
        __syncthreads();
    }
    #pragma unroll
    for (int n = 0; n < 6; ++n) {
        int m = m0 + n * 16 + ln;
        #pragma unroll
        for (int r = 0; r < 4; ++r) {
            int i = i0 + wid * 16 + kl * 4 + r;
            S1[(((size_t)kk * 192 + m) << 10) + i] = (_Float16)acc[n][r];
        }
    }
}

// S2[b][k][t][i] = sum_j (1024 A[b][i][j]) S1[k][b*12+t][j]  (f32 out). grid 256
__global__ __launch_bounds__(256) void k_s2b(const float* __restrict__ A,
                                             const _Float16* __restrict__ S1,
                                             float* __restrict__ S2) {
    int bx = blockIdx.x; int it = bx & 15, b = bx >> 4; int i0 = it * 64;
    __shared__ _Float16 sA[64][72], sB[48][72];
    int tid = threadIdx.x, wid = tid >> 6, ln = tid & 15, kl = (tid & 63) >> 4;
    const float* Ab = A + (size_t)b * N_ * N_;
    f32x4 acc[3];
    #pragma unroll
    for (int n = 0; n < 3; ++n) acc[n] = (f32x4){0.f, 0.f, 0.f, 0.f};
    for (int kc = 0; kc < N_; kc += 64) {
        #pragma unroll
        for (int it2 = 0; it2 < 4; ++it2) {
            int idx = it2 * 256 + tid; int row = idx >> 4, c4 = (idx & 15) * 4;
            float4 a4 = *(const float4*)&Ab[(size_t)(i0 + row) * N_ + kc + c4];
            f16x4 hv = {(_Float16)(a4.x * 1024.f), (_Float16)(a4.y * 1024.f),
                        (_Float16)(a4.z * 1024.f), (_Float16)(a4.w * 1024.f)};
            *(f16x4*)&sA[row][c4] = hv;
        }
        for (int idx = tid; idx < 288; idx += 256) {
            int row = idx >> 3, c8 = (idx & 7) * 8;
            int kq = row / 12, tq = row - kq * 12;
            *(uint4*)&sB[row][c8] = *(const uint4*)&S1[(((size_t)kq * 192 + b * T_ + tq) << 10) + kc + c8];
        }
        __syncthreads();
        #pragma unroll
        for (int ks = 0; ks < 4; ++ks) {
            int ko = ks * 16 + kl * 4;
            f16x4 a = *(const f16x4*)&sA[wid * 16 + ln][ko];
            #pragma unroll
            for (int n = 0; n < 3; ++n) {
                f16x4 b = *(const f16x4*)&sB[n * 16 + ln][ko];
                acc[n] = __builtin_amdgcn_mfma_f32_16x16x16f16(a, b, acc[n], 0, 0, 0);
            }
        }
        __syncthreads();
    }
    #pragma unroll
    for (int n = 0; n < 3; ++n) {
        int col = n * 16 + ln;
        if (col < 36) {
            int kq = col / 12, tq = col - kq * 12;
            #pragma unroll
            for (int r = 0; r < 4; ++r) {
                int i = i0 + wid * 16 + kl * 4 + r;
                S2[(((size_t)(b * 3 + kq) * T_ + tq) << 10) + i] = acc[n][r];
            }
        }
    }
}

// Stage 1: Yt[b][kk*64+c][i] = sum_j Ht[b][c][j] G[kk][i][j]. grid 768: (kk*16+it)*16+b
__global__ __launch_bounds__(256) void k_gh2(const float* __restrict__ G,
                                             const _Float16* __restrict__ Ht,
                                             _Float16* __restrict__ Yt) {
    int bx = blockIdx.x;
    int b = bx & 15, rest = bx >> 4;
    int it = rest & 15, kk = rest >> 4;
    int i0 = it * 64;
    __shared__ _Float16 sA[64][72], sB[64][72];
    int tid = threadIdx.x, wid = tid >> 6, ln = tid & 15, kl = (tid & 63) >> 4;
    const float* Gk = G + (size_t)kk * N_ * N_;
    const _Float16* Hb = Ht + ((size_t)b << 16);
    f32x4 acc[4];
    #pragma unroll
    for (int m = 0; m < 4; ++m) acc[m] = (f32x4){0.f, 0.f, 0.f, 0.f};
    for (int kc = 0; kc < N_; kc += 64) {
        #pragma unroll
        for (int it2 = 0; it2 < 2; ++it2) {          // Ht: 64x64 halves direct copy
            int idx = it2 * 256 + tid; int row = idx >> 3, c8 = (idx & 7) * 8;
            *(uint4*)&sA[row][c8] = *(const uint4*)&Hb[((size_t)row << 10) + kc + c8];
        }
        #pragma unroll
        for (int it2 = 0; it2 < 4; ++it2) {          // G: 64x64 f32 -> f16
            int idx = it2 * 256 + tid; int row = idx >> 4, c4 = (idx & 15) * 4;
            float4 g = *(const float4*)&Gk[(size_t)(i0 + row) * N_ + kc + c4];
            f16x4 hv = {(_Float16)g.x, (_Float16)g.y, (_Float16)g.z, (_Float16)g.w};
            *(f16x4*)&sB[row][c4] = hv;
        }
        __syncthreads();
        #pragma unroll
        for (int ks = 0; ks < 4; ++ks) {
            int ko = ks * 16 + kl * 4;
            f16x4 bfr = *(const f16x4*)&sB[wid * 16 + ln][ko];
            #pragma unroll
            for (int m = 0; m < 4; ++m) {
                f16x4 a = *(const f16x4*)&sA[m * 16 + ln][ko];
                acc[m] = __builtin_amdgcn_mfma_f32_16x16x16f16(a, bfr, acc[m], 0, 0, 0);
            }
        }
        __syncthreads();
    }
    int i = i0 + wid * 16 + ln;
    #pragma unroll
    for (int m = 0; m < 4; ++m)
        #pragma unroll
        for (int r = 0; r < 4; ++r) {
            int c = m * 16 + kl * 4 + r;
            Yt[(((size_t)b * 192 + kk * 64 + c) << 10) + i] = (_Float16)acc[m][r];
        }
}

// Stage 2: Zf[b][i][c] = sum_j (1024 A[b][i][j]) Yt[b][c][j]  (f16 out). grid 512
__global__ __launch_bounds__(256) void k_az2(const float* __restrict__ A,
                                             const _Float16* __restrict__ Yt,
                                             _Float16* __restrict__ Zf) {
    int bx = blockIdx.x;
    int nh = bx & 1, it = (bx >> 1) & 15, b = bx >> 5;
    int i0 = it * 64, c0 = nh * 96;
    __shared__ _Float16 sA[64][72], sB[96][72];
    int tid = threadIdx.x, wid = tid >> 6, ln = tid & 15, kl = (tid & 63) >> 4;
    const float* Ab = A + (size_t)b * N_ * N_;
    const _Float16* Yb = Yt + (((size_t)b * 192 + c0) << 10);
    f32x4 acc[6];
    #pragma unroll
    for (int n = 0; n < 6; ++n) acc[n] = (f32x4){0.f, 0.f, 0.f, 0.f};
    for (int kc = 0; kc < N_; kc += 64) {
        #pragma unroll
        for (int it2 = 0; it2 < 4; ++it2) {
            int idx = it2 * 256 + tid; int row = idx >> 4, c4 = (idx & 15) * 4;
            float4 a4 = *(const float4*)&Ab[(size_t)(i0 + row) * N_ + kc + c4];
            f16x4 hv = {(_Float16)(a4.x * 1024.f), (_Float16)(a4.y * 1024.f),
                        (_Float16)(a4.z * 1024.f), (_Float16)(a4.w * 1024.f)};
            *(f16x4*)&sA[row][c4] = hv;
        }
        #pragma unroll
        for (int it2 = 0; it2 < 3; ++it2) {
            int idx = it2 * 256 + tid; int row = idx >> 3, c8 = (idx & 7) * 8;
            *(uint4*)&sB[row][c8] = *(const uint4*)&Yb[((size_t)row << 10) + kc + c8];
        }
        __syncthreads();
        #pragma unroll
        for (int ks = 0; ks < 4; ++ks) {
            int ko = ks * 16 + kl * 4;
            f16x4 a = *(const f16x4*)&sA[wid * 16 + ln][ko];
            #pragma unroll
            for (int n = 0; n < 6; ++n) {
                f16x4 b = *(const f16x4*)&sB[n * 16 + ln][ko];
                acc[n] = __builtin_amdgcn_mfma_f32_16x16x16f16(a, b, acc[n], 0, 0, 0);
            }
        }
        __syncthreads();
    }
    #pragma unroll
    for (int n = 0; n < 6; ++n) {
        int c = c0 + n * 16 + ln;
        #pragma unroll
        for (int r = 0; r < 4; ++r) {
            int i = i0 + wid * 16 + kl * 4 + r;
            Zf[((size_t)((b << 10) + i)) * 192 + c] = (_Float16)acc[n][r];
        }
    }
}

// gate epilogue via MFMA: pre = Z@wghT^T + xt + bias; z->zb; r*h -> Ht. grid 256
__global__ __launch_bounds__(256) void k_zrm(const _Float16* __restrict__ Zf,
                                             const _Float16* __restrict__ wghT,
                                             const float* __restrict__ wx,
                                             const float* __restrict__ bg,
                                             const float* __restrict__ S2,
                                             const float* __restrict__ h,
                                             float* __restrict__ zb,
                                             _Float16* __restrict__ Ht, int t) {
    int bx = blockIdx.x; int it = bx & 15, b = bx >> 4; int i0 = it * 64;
    __shared__ _Float16 sZ[64][200];
    __shared__ _Float16 sW[128][72];
    __shared__ float sS2[3][64];
    __shared__ float sWX[3][128];
    __shared__ float sBias[128];
    int tid = threadIdx.x, wid = tid >> 6, ln = tid & 15, kl = (tid & 63) >> 4;
    #pragma unroll
    for (int it2 = 0; it2 < 6; ++it2) {
        int idx = it2 * 256 + tid; int row = idx / 24, c8 = (idx % 24) * 8;
        *(uint4*)&sZ[row][c8] = *(const uint4*)&Zf[((size_t)((b << 10) + i0 + row)) * 192 + c8];
    }
    if (tid < 192) { int k = tid >> 6, ii = tid & 63; sS2[k][ii] = S2[(((size_t)(b * 3 + k) * T_ + t) << 10) + i0 + ii]; }
    for (int q = tid; q < 384; q += 256) sWX[q >> 7][q & 127] = wx[q];
    if (tid < 128) sBias[tid] = bg[tid];
    f32x4 acc[4][2];
    #pragma unroll
    for (int m = 0; m < 4; ++m)
        #pragma unroll
        for (int n = 0; n < 2; ++n) acc[m][n] = (f32x4){0.f, 0.f, 0.f, 0.f};
    for (int kc = 0; kc < 192; kc += 64) {
        #pragma unroll
        for (int it2 = 0; it2 < 4; ++it2) {
            int idx = it2 * 256 + tid; int row = idx >> 3, c8 = (idx & 7) * 8;
            *(uint4*)&sW[row][c8] = *(const uint4*)&wghT[(size_t)row * 192 + kc + c8];
        }
        __syncthreads();
        #pragma unroll
        for (int ks = 0; ks < 4; ++ks) {
            int ko = ks * 16 + kl * 4;
            f16x4 a[4], bb[2];
            #pragma unroll
            for (int m = 0; m < 4; ++m) a[m] = *(const f16x4*)&sZ[m * 16 + ln][kc + ko];
            #pragma unroll
            for (int n = 0; n < 2; ++n) bb[n] = *(const f16x4*)&sW[wid * 32 + n * 16 + ln][ko];
            #pragma unroll
            for (int m = 0; m < 4; ++m)
                #pragma unroll
                for (int n = 0; n < 2; ++n)
                    acc[m][n] = __builtin_amdgcn_mfma_f32_16x16x16f16(a[m], bb[n], acc[m][n], 0, 0, 0);
        }
        __syncthreads();
    }
    #pragma unroll
    for (int n = 0; n < 2; ++n) {
        int o = wid * 32 + n * 16 + ln;
        float wx0 = sWX[0][o], wx1 = sWX[1][o], wx2 = sWX[2][o], bias = sBias[o];
        if (o < H_) {
            #pragma unroll
            for (int m = 0; m < 4; ++m)
                #pragma unroll
                for (int r = 0; r < 4; ++r) {
                    int il = m * 16 + kl * 4 + r;
                    float pre = acc[m][n][r] + wx0 * sS2[0][il] + wx1 * sS2[1][il] + wx2 * sS2[2][il] + bias;
                    float v = 1.0f / (1.0f + expf(-pre));
                    zb[((size_t)((b << 10) + i0 + il)) * H_ + o] = v;
                }
        } else {
            int c = o - H_;
            #pragma unroll
            for (int m = 0; m < 4; ++m) {
                alignas(8) _Float16 hb[4];
                #pragma unroll
                for (int r = 0; r < 4; ++r) {
                    int il = m * 16 + kl * 4 + r;
                    float pre = acc[m][n][r] + wx0 * sS2[0][il] + wx1 * sS2[1][il] + wx2 * sS2[2][il] + bias;
                    float v = 1.0f / (1.0f + expf(-pre));
                    hb[r] = (_Float16)(v * h[((size_t)((b << 10) + i0 + il)) * H_ + c]);
                }
                *(f16x4*)&Ht[(((size_t)(b * 64 + c)) << 10) + i0 + m * 16 + kl * 4] = *(f16x4*)&hb[0];
            }
        }
    }
}

// update epilogue via MFMA: hc = tanh(...); h = z*hc + (1-z)h; write h f32 + Ht f16. grid 256
__global__ __launch_bounds__(256) void k_updm(const _Float16* __restrict__ Zf,
                                              const _Float16* __restrict__ wuhT,
                                              const float* __restrict__ wx,
                                              const float* __restrict__ bu,
                                              const float* __restrict__ S2,
                                              const float* __restrict__ zb,
                                              float* __restrict__ h,
                                              _Float16* __restrict__ Ht, int t) {
    int bx = blockIdx.x; int it = bx & 15, b = bx >> 4; int i0 = it * 64;
    __shared__ _Float16 sZ[64][200];
    __shared__ _Float16 sW[64][72];
    __shared__ float sS2[3][64];
    __shared__ float sWX[3][64];
    __shared__ float sBias[64];
    int tid = threadIdx.x, wid = tid >> 6, ln = tid & 15, kl = (tid & 63) >> 4;
    #pragma unroll
    for (int it2 = 0; it2 < 6; ++it2) {
        int idx = it2 * 256 + tid; int row = idx / 24, c8 = (idx % 24) * 8;
        *(uint4*)&sZ[row][c8] = *(const uint4*)&Zf[((size_t)((b << 10) + i0 + row)) * 192 + c8];
    }
    if (tid < 192) { int k = tid >> 6, ii = tid & 63; sS2[k][ii] = S2[(((size_t)(b * 3 + k) * T_ + t) << 10) + i0 + ii]; }
    if (tid < 192) sWX[tid / 64][tid % 64] = wx[384 + tid];
    if (tid < 64) sBias[tid] = bu[tid];
    f32x4 acc[4];
    #pragma unroll
    for (int m = 0; m < 4; ++m) acc[m] = (f32x4){0.f, 0.f, 0.f, 0.f};
    for (int kc = 0; kc < 192; kc += 64) {
        #pragma unroll
        for (int it2 = 0; it2 < 2; ++it2) {
            int idx = it2 * 256 + tid; int row = idx >> 3, c8 = (idx & 7) * 8;
            *(uint4*)&sW[row][c8] = *(const uint4*)&wuhT[(size_t)row * 192 + kc + c8];
        }
        __syncthreads();
        #pragma unroll
        for (int ks = 0; ks < 4; ++ks) {
            int ko = ks * 16 + kl * 4;
            f16x4 bb = *(const f16x4*)&sW[wid * 16 + ln][ko];
            #pragma unroll
            for (int m = 0; m < 4; ++m) {
                f16x4 a = *(const f16x4*)&sZ[m * 16 + ln][kc + ko];
                acc[m] = __builtin_amdgcn_mfma_f32_16x16x16f16(a, bb, acc[m], 0, 0, 0);
            }
        }
        __syncthreads();
    }
    int o = wid * 16 + ln;
    float wx0 = sWX[0][o], wx1 = sWX[1][o], wx2 = sWX[2][o], bias = sBias[o];
    #pragma unroll
    for (int m = 0; m < 4; ++m) {
        alignas(8) _Float16 hb[4];
        #pragma unroll
        for (int r = 0; r < 4; ++r) {
            int il = m * 16 + kl * 4 + r;
            float pre = acc[m][r] + wx0 * sS2[0][il] + wx1 * sS2[1][il] + wx2 * sS2[2][il] + bias;
            float hc = tanhf(pre);
            size_t gi = ((size_t)((b << 10) + i0 + il)) * H_ + o;
            float z = zb[gi], hold = h[gi];
            float hn = z * hc + (1.0f - z) * hold;
            h[gi] = hn;
            hb[r] = (_Float16)hn;
        }
        *(f16x4*)&Ht[(((size_t)(b * 64 + o)) << 10) + i0 + m * 16 + kl * 4] = *(f16x4*)&hb[0];
    }
}

// out[(b*12+tt)*1024 + i] = h[b][i][:] @ W_dec[:,tt] + b_dec[tt]
__global__ __launch_bounds__(256) void k_dec(const float* __restrict__ h,
                                             const float* __restrict__ Wd,
                                             const float* __restrict__ bd,
                                             float* __restrict__ out) {
    int bx = blockIdx.x;
    int b = bx >> 4, it = bx & 15; int i0 = it * 64;
    __shared__ float hs[64][65];
    __shared__ float Wds[64][12];
    __shared__ float bds[12];
    int tid = threadIdx.x;
    for (int idx = tid; idx < 4096; idx += 256) {
        int r = idx >> 6, c = idx & 63;
        hs[r][c] = h[(size_t)(b * N_ + i0 + r) * H_ + c];
    }
    for (int idx = tid; idx < 768; idx += 256)
        Wds[idx / 12][idx % 12] = Wd[idx];
    if (tid < 12) bds[tid] = bd[tid];
    __syncthreads();
    for (int oidx = tid; oidx < 768; oidx += 256) {
        int i = oidx & 63, tt = oidx >> 6;
        float acc = bds[tt];
        #pragma unroll
        for (int c = 0; c < 64; ++c) acc += hs[i][c] * Wds[c][tt];
        out[(size_t)(b * T_ + tt) * N_ + i0 + i] = acc;
    }
}

extern "C" void kernel_launch(void* const* d_in, const int* in_sizes, int n_in,
                              void* d_out, int out_size, void* d_ws, size_t ws_size,
                              hipStream_t stream) {
    const float* x  = (const float*)d_in[0];
    const float* G  = (const float*)d_in[1];
    const float* A  = (const float*)d_in[2];
    const float* Wg = (const float*)d_in[3];
    const float* bg = (const float*)d_in[4];
    const float* Wu = (const float*)d_in[5];
    const float* bu = (const float*)d_in[6];
    const float* Wd = (const float*)d_in[7];
    const float* bd = (const float*)d_in[8];
    float* out = (float*)d_out;
    float* ws  = (float*)d_ws;

    float* h   = ws + OFF_H;
    float* zb  = ws + OFF_ZB;
    float* S2  = ws + OFF_S2;
    float* wxb = ws + OFF_WX;
    _Float16* Zf   = (_Float16*)(ws + OFF_ZF);
    _Float16* Ht   = (_Float16*)(ws + OFF_HT);
    _Float16* Yt   = (_Float16*)(ws + OFF_YT);
    _Float16* S1   = (_Float16*)(ws + OFF_S1);
    _Float16* wghT = (_Float16*)(ws + OFF_WGT);
    _Float16* wuhT = (_Float16*)(ws + OFF_WUT);

    hipMemsetAsync(h, 0, (size_t)B_ * N_ * H_ * sizeof(float), stream);
    hipMemsetAsync((void*)Ht, 0, (size_t)B_ * N_ * H_ * sizeof(_Float16), stream);
    k_repack<<<147, 256, 0, stream>>>(Wg, Wu, wghT, wuhT, wxb);
    k_s1b<<<96, 256, 0, stream>>>(G, x, S1);
    k_s2b<<<256, 256, 0, stream>>>(A, S1, S2);

    for (int t = 0; t < T_; ++t) {
        k_gh2<<<768, 256, 0, stream>>>(G, Ht, Yt);
        k_az2<<<512, 256, 0, stream>>>(A, Yt, Zf);
        k_zrm<<<256, 256, 0, stream>>>(Zf, wghT, wxb, bg, S2, h, zb, Ht, t);
        k_gh2<<<768, 256, 0, stream>>>(G, Ht, Yt);
        k_az2<<<512, 256, 0, stream>>>(A, Yt, Zf);
        k_updm<<<256, 256, 0, stream>>>(Zf, wuhT, wxb, bu, S2, zb, h, Ht, t);
    }
    k_dec<<<256, 256, 0, stream>>>(h, Wd, bd, out);
}